// Round 3
// baseline (158.555 us; speedup 1.0000x reference)
//
#include <hip/hip_runtime.h>
#include <stdint.h>

// ---------------------------------------------------------------------------
// Fused MHA block: qkv proj -> flash attention -> out proj.
// Inputs fp32, output fp32; bf16 MFMA compute, fp32 accum.
// B=4 N=2048 C=512 H=8 D=64 fixed.
// R20: attn_fused = 512 threads / 8 waves; wave (qq,kh) owns 32 q-rows x
// 64 kv-cols. Same per-CU work as R19 but 4 waves/SIMD (vs 2) to hide the
// measured ~60% stall fraction (R18 1w=63us vs R19 2w=44us proves
// stall-bound). Per-wave regs shrink (oacc 32, qf 16) to fit 128-VGPR cap
// via __launch_bounds__(512,4). kh-partials merged via one LDS round.
// ---------------------------------------------------------------------------

typedef short bf16x8 __attribute__((ext_vector_type(8)));   // 8 bf16 = 4 VGPRs
typedef float f32x2  __attribute__((ext_vector_type(2)));
typedef float f32x4  __attribute__((ext_vector_type(4)));
typedef float f32x16 __attribute__((ext_vector_type(16)));
typedef unsigned int u32x4 __attribute__((ext_vector_type(4)));

__device__ __forceinline__ unsigned short f2bf(float f) {
    unsigned int u = __builtin_bit_cast(unsigned int, f);
    u += 0x7fffu + ((u >> 16) & 1u);
    return (unsigned short)(u >> 16);
}
__device__ __forceinline__ unsigned int pk2(float a, float b) {
    return (unsigned int)f2bf(a) | ((unsigned int)f2bf(b) << 16);
}
__device__ __forceinline__ float fexp2(float x) {
    return __builtin_amdgcn_exp2f(x);    // bare v_exp_f32
}
__device__ __forceinline__ bf16x8 ld8_f32(const float* __restrict__ p) {
    float4 f0 = *(const float4*)p;
    float4 f1 = *(const float4*)(p + 4);
    u32x4 u = {pk2(f0.x, f0.y), pk2(f0.z, f0.w), pk2(f1.x, f1.y), pk2(f1.z, f1.w)};
    return __builtin_bit_cast(bf16x8, u);
}
__device__ __forceinline__ void async16(const void* g, void* l) {
    __builtin_amdgcn_global_load_lds(
        (const __attribute__((address_space(1))) unsigned int*)g,
        (__attribute__((address_space(3))) unsigned int*)l,
        16, 0, 0);
}

#define MFMA16(a, b, c) __builtin_amdgcn_mfma_f32_16x16x32_bf16((a), (b), (c), 0, 0, 0)
#define MFMA32(a, b, c) __builtin_amdgcn_mfma_f32_32x32x16_bf16((a), (b), (c), 0, 0, 0)

// ---------------------------------------------------------------------------
// fp32 -> bf16 bulk convert: x, qkv_w, proj_w in one pass.
// ---------------------------------------------------------------------------
__global__ void cvt_bf16(const float* __restrict__ x,
                         const float* __restrict__ w,
                         const float* __restrict__ w2,
                         unsigned short* __restrict__ xb,
                         unsigned short* __restrict__ wb,
                         unsigned short* __restrict__ wb2)
{
    const int G = 524288 + 98304 + 32768;
    for (int idx = blockIdx.x * 256 + threadIdx.x; idx < G; idx += gridDim.x * 256) {
        if (idx < 524288)
            *(bf16x8*)(xb + (size_t)idx * 8) = ld8_f32(x + (size_t)idx * 8);
        else if (idx < 524288 + 98304) {
            int j = idx - 524288;
            *(bf16x8*)(wb + (size_t)j * 8) = ld8_f32(w + (size_t)j * 8);
        } else {
            int j = idx - 524288 - 98304;
            *(bf16x8*)(wb2 + (size_t)j * 8) = ld8_f32(w2 + (size_t)j * 8);
        }
    }
}

// ---------------------------------------------------------------------------
// QKV GEMM: 128x128 tile / 4 waves; BK=32; dual DMA staging; 4 blocks/CU.
// XCD remap: XCD k owns A-rows [8k,8k+8) x all 12 col-tiles.
// ---------------------------------------------------------------------------
__global__ __launch_bounds__(256, 4)
void gemm_qkv(const unsigned short* __restrict__ A,
              const unsigned short* __restrict__ B,
              const float* __restrict__ bias,
              unsigned short* __restrict__ out0,
              unsigned short* __restrict__ out1,
              unsigned short* __restrict__ out2,
              int K)
{
    __shared__ unsigned short sA[128 * 32];
    __shared__ unsigned short sB[128 * 32];

    const int tid  = threadIdx.x;
    const int wave = tid >> 6, lane = tid & 63;
    const int l = lane & 15, q16 = lane >> 4;
    const int wm = wave >> 1, wn = wave & 1;
    const int bid = blockIdx.x;                  // 0..767
    const int slot = bid >> 3;                   // 0..95
    const int m0 = ((bid & 7) * 8 + slot / 12) * 128;
    const int n0 = (slot % 12) * 128;

    f32x4 acc[4][4];
#pragma unroll
    for (int i = 0; i < 4; ++i)
#pragma unroll
        for (int j = 0; j < 4; ++j)
            acc[i][j] = (f32x4){0.f, 0.f, 0.f, 0.f};

    for (int k0 = 0; k0 < K; k0 += 32) {
#pragma unroll
        for (int call = 0; call < 2; ++call) {
            int L = call * 256 + tid;
            int r = L >> 2, c = L & 3;
            async16(A + (size_t)(m0 + r) * K + k0 + c * 8, sA + L * 8);
            async16(B + (size_t)(n0 + r) * K + k0 + c * 8, sB + L * 8);
        }
        __syncthreads();

        bf16x8 af[4], bfr[4];
#pragma unroll
        for (int i = 0; i < 4; ++i)
            af[i] = *(const bf16x8*)(sA + ((wm * 64 + i * 16 + l) * 4 + q16) * 8);
#pragma unroll
        for (int j = 0; j < 4; ++j)
            bfr[j] = *(const bf16x8*)(sB + ((wn * 64 + j * 16 + l) * 4 + q16) * 8);
#pragma unroll
        for (int i = 0; i < 4; ++i)
#pragma unroll
            for (int j = 0; j < 4; ++j)
                acc[i][j] = MFMA16(af[i], bfr[j], acc[i][j]);
        __syncthreads();
    }

    const float lscale = 0.18033688f;  // D^-0.5 * log2(e), folded into q
#pragma unroll
    for (int i = 0; i < 4; ++i) {
#pragma unroll
        for (int j = 0; j < 4; ++j) {
            int col = n0 + wn * 64 + j * 16 + l;
            float bv = bias[col];
#pragma unroll
            for (int r = 0; r < 4; ++r) {
                int row = m0 + wm * 64 + i * 16 + q16 * 4 + r;
                float val = acc[i][j][r] + bv;
                int which = col >> 9;            // 0:q 1:k 2:v
                int h = (col >> 6) & 7, d = col & 63;
                int b = row >> 11, n = row & 2047;
                if (which == 0)
                    out0[(size_t)(((b * 8 + h) * 2048) + n) * 64 + d] = f2bf(val * lscale);
                else if (which == 1)
                    out1[(size_t)(((b * 8 + h) * 2048) + n) * 64 + d] = f2bf(val);
                else {
                    // V^T with pi(n): swap bits 2<->3 of n (within 32-blocks)
                    int np = (n & ~12) | ((n & 8) >> 1) | ((n & 4) << 1);
                    out2[(size_t)(((b * 8 + h) * 64) + d) * 2048 + np] = f2bf(val);
                }
            }
        }
    }
}

// ---------------------------------------------------------------------------
// Output GEMM: 64x128 tile / 4 waves; BK=32; 4 blocks/CU. fp32 out + bias.
// XCD remap: XCD k owns rows [16k,16k+16) x 4 col-tiles.
// ---------------------------------------------------------------------------
__global__ __launch_bounds__(256, 4)
void gemm_out(const unsigned short* __restrict__ A,
              const unsigned short* __restrict__ B,
              const float* __restrict__ bias,
              float* __restrict__ outf,
              int K, int N)
{
    __shared__ unsigned short sA[64 * 32];
    __shared__ unsigned short sB[128 * 32];

    const int tid  = threadIdx.x;
    const int wave = tid >> 6, lane = tid & 63;
    const int l = lane & 15, q16 = lane >> 4;
    const int wm = wave >> 1, wn = wave & 1;
    const int bid = blockIdx.x;                  // 0..511
    const int slot = bid >> 3;                   // 0..63
    const int m0 = ((bid & 7) * 16 + (slot >> 2)) * 64;
    const int n0 = (slot & 3) * 128;

    f32x4 acc[2][4];
#pragma unroll
    for (int i = 0; i < 2; ++i)
#pragma unroll
        for (int j = 0; j < 4; ++j)
            acc[i][j] = (f32x4){0.f, 0.f, 0.f, 0.f};

    for (int k0 = 0; k0 < K; k0 += 32) {
        {
            int r = tid >> 2, c = tid & 3;       // A: 256 slots
            async16(A + (size_t)(m0 + r) * K + k0 + c * 8, sA + tid * 8);
        }
#pragma unroll
        for (int call = 0; call < 2; ++call) {   // B: 512 slots
            int L = call * 256 + tid;
            int r = L >> 2, c = L & 3;
            async16(B + (size_t)(n0 + r) * K + k0 + c * 8, sB + L * 8);
        }
        __syncthreads();

        bf16x8 af[2], bfr[4];
#pragma unroll
        for (int i = 0; i < 2; ++i)
            af[i] = *(const bf16x8*)(sA + ((wm * 32 + i * 16 + l) * 4 + q16) * 8);
#pragma unroll
        for (int j = 0; j < 4; ++j)
            bfr[j] = *(const bf16x8*)(sB + ((wn * 64 + j * 16 + l) * 4 + q16) * 8);
#pragma unroll
        for (int i = 0; i < 2; ++i)
#pragma unroll
            for (int j = 0; j < 4; ++j)
                acc[i][j] = MFMA16(af[i], bfr[j], acc[i][j]);
        __syncthreads();
    }

#pragma unroll
    for (int i = 0; i < 2; ++i) {
#pragma unroll
        for (int j = 0; j < 4; ++j) {
            int col = n0 + wn * 64 + j * 16 + l;
            float bv = bias[col];
#pragma unroll
            for (int r = 0; r < 4; ++r) {
                int row = m0 + wm * 32 + i * 16 + q16 * 4 + r;
                outf[(size_t)row * N + col] = acc[i][j][r] + bv;
            }
        }
    }
}

// ---------------------------------------------------------------------------
// Flash attention R20: 512 threads / 8 waves; wave (qq,kh): q-rows
// qq*32..+31 vs kv-half kh*64..+63 of each 128-kv tile. 16 ds_read_b128 /
// 16 MFMA32 per wave per iter; 2 blocks/CU -> 4 waves/SIMD. kh partials
// merged additively via one LDS round (static-max softmax).
// ---------------------------------------------------------------------------
__global__ __launch_bounds__(512, 4)
void attn_fused(const unsigned short* __restrict__ Q,
                const unsigned short* __restrict__ Km,
                const unsigned short* __restrict__ Vt,
                unsigned short* __restrict__ O)
{
    __shared__ unsigned short sAll[32768];       // 64 KB: K[2][8192] | V[2][8192]

    const int tid  = threadIdx.x;
    const int wave = tid >> 6, lane = tid & 63;
    const int l31 = lane & 31, h = lane >> 5;
    const int swz = l31 & 7;
    const int qq = wave >> 1, kh = wave & 1;     // qq 0..3, kh 0..1
    const int bid = blockIdx.x;                  // 0..511
    const int slot = bid >> 3;                   // 0..63
    const int bh = (bid & 7) * 4 + (slot >> 4);  // 4 heads per XCD
    const int n0 = (slot & 15) * 128;
    const int q0 = n0 + qq * 32;                 // this wave: q0..q0+31

    const unsigned short* Kp = Km + (size_t)bh * 2048 * 64;
    const unsigned short* Vp = Vt + (size_t)bh * 64 * 2048;
    unsigned short* sKf = sAll;                  // two 8192-elem buffers
    unsigned short* sVf = sAll + 16384;          // two 8192-elem buffers

    // K fragment addrs: row = kh*64 + mt*32 + l31 (row&7 == swz),
    // chunk = (ks*2+h)^swz. mt*2048 added at use.
    int ka[4], va[2][2];
#pragma unroll
    for (int ks = 0; ks < 4; ++ks)
        ka[ks] = (kh * 64 + l31) * 64 + ((ks * 2 + h) ^ swz) * 8;
    // V^T fragment addrs: row = d = l31 (+dt*32 at use), kv chunk
    // kh*8 + (m1*4+ks2*2+h): low-3-bit XOR swizzle, +kh*64 raw col offset.
#pragma unroll
    for (int m1 = 0; m1 < 2; ++m1)
#pragma unroll
        for (int ks2 = 0; ks2 < 2; ++ks2)
            va[m1][ks2] = l31 * 128 + ((m1 * 4 + ks2 * 2 + h) ^ swz) * 8 + kh * 64;

    // staging: 1024 slots of 8 elems, 512 threads -> 2 calls each for K and V
    int ksrc[2], vsrc[2], dstv[2];
#pragma unroll
    for (int c = 0; c < 2; ++c) {
        int s = c * 512 + tid;
        int rk = s >> 3;
        ksrc[c] = rk * 64 + ((s & 7) ^ (rk & 7)) * 8;
        int rv = s >> 4;
        vsrc[c] = rv * 2048 + ((s & 15) ^ (rv & 7)) * 8;
        dstv[c] = s * 8;
    }

    bf16x8 qf[4];
#pragma unroll
    for (int ks = 0; ks < 4; ++ks)
        qf[ks] = *(const bf16x8*)(Q + (size_t)(bh * 2048 + q0 + l31) * 64
                                  + ks * 16 + h * 8);

    f32x16 oacc[2];
#pragma unroll
    for (int dt = 0; dt < 2; ++dt)
#pragma unroll
        for (int e = 0; e < 16; ++e) oacc[dt][e] = 0.f;
    f32x16 Zv;
#pragma unroll
    for (int e = 0; e < 16; ++e) Zv[e] = 0.f;
    f32x2 l2 = {0.f, 0.f};

#pragma unroll
    for (int c = 0; c < 2; ++c) {
        async16(Kp + ksrc[c], (void*)(sKf + dstv[c]));
        async16(Vp + vsrc[c], (void*)(sVf + dstv[c]));
    }
    __syncthreads();

    for (int it = 0; it < 16; ++it) {
        const int nb = ((it + 1) & 1) * 8192;
        if (it < 15) {
            int kv = (it + 1) * 128;
#pragma unroll
            for (int c = 0; c < 2; ++c)
                async16(Kp + (size_t)kv * 64 + ksrc[c], (void*)(sKf + nb + dstv[c]));
        }

        // QK^T for this wave's kv-half: 8 K reads feed 8 MFMAs.
        f32x16 sacc[2];
#pragma unroll
        for (int mt = 0; mt < 2; ++mt) {
            bf16x8 kf0 = *(const bf16x8*)(sKf + ka[0] + mt * 2048);
            sacc[mt] = MFMA32(kf0, qf[0], Zv);
#pragma unroll
            for (int ks = 1; ks < 4; ++ks) {
                bf16x8 kf = *(const bf16x8*)(sKf + ka[ks] + mt * 2048);
                sacc[mt] = MFMA32(kf, qf[ks], sacc[mt]);
            }
        }

        if (it < 15) {
            int kv = (it + 1) * 128;
#pragma unroll
            for (int c = 0; c < 2; ++c)
                async16(Vp + (size_t)kv + vsrc[c], (void*)(sVf + nb + dstv[c]));
        }

        // softmax + PV fused per 32-kv subtile mt; 8 V reads feed 8 MFMAs.
#pragma unroll
        for (int mt = 0; mt < 2; ++mt) {
            unsigned int pk[4][2];
#pragma unroll
            for (int g = 0; g < 4; ++g) {
                float p0 = fexp2(sacc[mt][4 * g + 0]);
                float p1 = fexp2(sacc[mt][4 * g + 1]);
                float p2 = fexp2(sacc[mt][4 * g + 2]);
                float p3 = fexp2(sacc[mt][4 * g + 3]);
                l2 += (f32x2){p0, p1};
                l2 += (f32x2){p2, p3};
                pk[g][0] = __builtin_amdgcn_perm(
                    __builtin_bit_cast(unsigned int, p1),
                    __builtin_bit_cast(unsigned int, p0), 0x07060302u);
                pk[g][1] = __builtin_amdgcn_perm(
                    __builtin_bit_cast(unsigned int, p3),
                    __builtin_bit_cast(unsigned int, p2), 0x07060302u);
            }
#pragma unroll
            for (int ks2 = 0; ks2 < 2; ++ks2) {
                u32x4 bu;
                bu[0] = pk[2 * ks2][0];
                bu[1] = pk[2 * ks2][1];
                bu[2] = pk[2 * ks2 + 1][0];
                bu[3] = pk[2 * ks2 + 1][1];
                bf16x8 bfrag = __builtin_bit_cast(bf16x8, bu);
#pragma unroll
                for (int dt = 0; dt < 2; ++dt) {
                    bf16x8 vf = *(const bf16x8*)(sVf + va[mt][ks2] + dt * 4096);
                    oacc[dt] = MFMA32(vf, bfrag, oacc[dt]);
                }
            }
        }

#pragma unroll
        for (int ks = 0; ks < 4; ++ks) ka[ks] ^= 8192;
        va[0][0] ^= 8192; va[0][1] ^= 8192; va[1][0] ^= 8192; va[1][1] ^= 8192;
        __syncthreads();
    }

    // ---- kh-half merge epilogue (loop exits right after __syncthreads) ----
    // kh=1 waves park partials in dead LDS; kh=0 waves add and write O.
    float* sf = (float*)sAll;            // 32 KB: oacc partials (4 waves x 8KB)
    float* sl = sf + 8192;               // 2 KB: l2 partials
    if (kh == 1) {
        const int base = qq * 2048 + lane * 32;
#pragma unroll
        for (int dt = 0; dt < 2; ++dt) {
            int chunk = dt ^ (lane & 1);         // bank de-phase
            *(f32x16*)(sf + base + chunk * 16) = oacc[dt];
        }
        *(f32x2*)(sl + qq * 128 + lane * 2) = l2;
    }
    __syncthreads();
    if (kh == 0) {
        const int base = qq * 2048 + lane * 32;
#pragma unroll
        for (int dt = 0; dt < 2; ++dt) {
            int chunk = dt ^ (lane & 1);
            f32x16 part = *(const f32x16*)(sf + base + chunk * 16);
#pragma unroll
            for (int e = 0; e < 16; ++e) oacc[dt][e] += part[e];
        }
        l2 += *(const f32x2*)(sl + qq * 128 + lane * 2);

        float l_run = l2[0] + l2[1];
        l_run += __shfl_xor(l_run, 32);
        float inv = 1.f / fmaxf(l_run, 1e-20f);
        const int b = bh >> 3, hh = bh & 7;
        unsigned short* obase = O + ((size_t)(b * 2048 + q0 + l31)) * 512 + hh * 64;
#pragma unroll
        for (int dt = 0; dt < 2; ++dt)
#pragma unroll
            for (int g = 0; g < 4; ++g) {
                int d = dt * 32 + 8 * g + 4 * h;
                unsigned int w0 = pk2(oacc[dt][4 * g + 0] * inv,
                                      oacc[dt][4 * g + 1] * inv);
                unsigned int w1 = pk2(oacc[dt][4 * g + 2] * inv,
                                      oacc[dt][4 * g + 3] * inv);
                uint2 w = {w0, w1};
                *(uint2*)(obase + d) = w;
            }
    }
}

// ---------------------------------------------------------------------------
extern "C" void kernel_launch(void* const* d_in, const int* in_sizes, int n_in,
                              void* d_out, int out_size, void* d_ws, size_t ws_size,
                              hipStream_t stream)
{
    const float* x      = (const float*)d_in[0];  // [4,2048,512]
    const float* qkv_w  = (const float*)d_in[1];  // [1536,512]
    const float* qkv_b  = (const float*)d_in[2];  // [1536]
    const float* proj_w = (const float*)d_in[3];  // [512,512]
    const float* proj_b = (const float*)d_in[4];  // [512]

    const size_t PER = 4u * 8u * 2048u * 64u;     // 4,194,304 elems (8 MB bf16)
    unsigned short* q_ws  = (unsigned short*)d_ws;
    unsigned short* k_ws  = q_ws  + PER;
    unsigned short* vt_ws = k_ws  + PER;
    unsigned short* ao_ws = vt_ws + PER;
    unsigned short* wb2   = ao_ws + PER;          // proj_w bf16 (0.5 MB)

    // bf16 scratch inside d_out (16 MB; dead until final GEMM overwrites it)
    unsigned short* xb = (unsigned short*)d_out;          // 8 MB
    unsigned short* wb = xb + PER;                        // 1.5 MB

    // 0) bulk fp32->bf16 of x, qkv_w, proj_w (one launch)
    cvt_bf16<<<dim3(640), 256, 0, stream>>>(x, qkv_w, proj_w, xb, wb, wb2);
    // 1) QKV projection: M=8192, N=1536, K=512 (XCD-remapped)
    gemm_qkv<<<dim3(768), 256, 0, stream>>>(xb, wb, qkv_b, q_ws, k_ws, vt_ws, 512);
    // 2) Flash attention: 512 blocks x 512 threads, 8 waves (qq,kh)
    attn_fused<<<dim3(512), 512, 0, stream>>>(q_ws, k_ws, vt_ws, ao_ws);
    // 3) Output projection: M=8192, N=512, K=512 (XCD-remapped)
    gemm_out<<<dim3(512), 256, 0, stream>>>(ao_ws, wb2, proj_b, (float*)d_out, 512, 512);
}

// Round 4
// 155.840 us; speedup vs baseline: 1.0174x; 1.0174x over previous
//
#include <hip/hip_runtime.h>
#include <stdint.h>

// ---------------------------------------------------------------------------
// Fused MHA block: qkv proj -> flash attention -> out proj.
// Inputs fp32, output fp32; bf16 MFMA compute, fp32 accum.
// B=4 N=2048 C=512 H=8 D=64 fixed.
// R21: attn_fused = 1024 threads / 16 waves / 1 block per CU; wave (qq,kh)
// owns 32 q-rows x 64 kv-cols. TRIPLE-buffered LDS (96KB) + depth-2
// prefetch + counted vmcnt(2) waits BEFORE raw s_barrier (T3/T4): no
// vmcnt(0) drain in the main loop (R14/R19/R20 all stuck at 43-46us from
// the __syncthreads drain aligning all waves). s_setprio(1) around MFMA
// clusters (T5). kh-partials merged additively via LDS epilogue.
// ---------------------------------------------------------------------------

typedef short bf16x8 __attribute__((ext_vector_type(8)));   // 8 bf16 = 4 VGPRs
typedef float f32x2  __attribute__((ext_vector_type(2)));
typedef float f32x4  __attribute__((ext_vector_type(4)));
typedef float f32x16 __attribute__((ext_vector_type(16)));
typedef unsigned int u32x4 __attribute__((ext_vector_type(4)));

__device__ __forceinline__ unsigned short f2bf(float f) {
    unsigned int u = __builtin_bit_cast(unsigned int, f);
    u += 0x7fffu + ((u >> 16) & 1u);
    return (unsigned short)(u >> 16);
}
__device__ __forceinline__ unsigned int pk2(float a, float b) {
    return (unsigned int)f2bf(a) | ((unsigned int)f2bf(b) << 16);
}
__device__ __forceinline__ float fexp2(float x) {
    return __builtin_amdgcn_exp2f(x);    // bare v_exp_f32
}
__device__ __forceinline__ bf16x8 ld8_f32(const float* __restrict__ p) {
    float4 f0 = *(const float4*)p;
    float4 f1 = *(const float4*)(p + 4);
    u32x4 u = {pk2(f0.x, f0.y), pk2(f0.z, f0.w), pk2(f1.x, f1.y), pk2(f1.z, f1.w)};
    return __builtin_bit_cast(bf16x8, u);
}
__device__ __forceinline__ void async16(const void* g, void* l) {
    __builtin_amdgcn_global_load_lds(
        (const __attribute__((address_space(1))) unsigned int*)g,
        (__attribute__((address_space(3))) unsigned int*)l,
        16, 0, 0);
}

#define MFMA16(a, b, c) __builtin_amdgcn_mfma_f32_16x16x32_bf16((a), (b), (c), 0, 0, 0)
#define MFMA32(a, b, c) __builtin_amdgcn_mfma_f32_32x32x16_bf16((a), (b), (c), 0, 0, 0)

// ---------------------------------------------------------------------------
// fp32 -> bf16 bulk convert: x, qkv_w, proj_w in one pass.
// ---------------------------------------------------------------------------
__global__ void cvt_bf16(const float* __restrict__ x,
                         const float* __restrict__ w,
                         const float* __restrict__ w2,
                         unsigned short* __restrict__ xb,
                         unsigned short* __restrict__ wb,
                         unsigned short* __restrict__ wb2)
{
    const int G = 524288 + 98304 + 32768;
    for (int idx = blockIdx.x * 256 + threadIdx.x; idx < G; idx += gridDim.x * 256) {
        if (idx < 524288)
            *(bf16x8*)(xb + (size_t)idx * 8) = ld8_f32(x + (size_t)idx * 8);
        else if (idx < 524288 + 98304) {
            int j = idx - 524288;
            *(bf16x8*)(wb + (size_t)j * 8) = ld8_f32(w + (size_t)j * 8);
        } else {
            int j = idx - 524288 - 98304;
            *(bf16x8*)(wb2 + (size_t)j * 8) = ld8_f32(w2 + (size_t)j * 8);
        }
    }
}

// ---------------------------------------------------------------------------
// QKV GEMM: 128x128 tile / 4 waves; BK=32; dual DMA staging; 4 blocks/CU.
// XCD remap: XCD k owns A-rows [8k,8k+8) x all 12 col-tiles.
// ---------------------------------------------------------------------------
__global__ __launch_bounds__(256, 4)
void gemm_qkv(const unsigned short* __restrict__ A,
              const unsigned short* __restrict__ B,
              const float* __restrict__ bias,
              unsigned short* __restrict__ out0,
              unsigned short* __restrict__ out1,
              unsigned short* __restrict__ out2,
              int K)
{
    __shared__ unsigned short sA[128 * 32];
    __shared__ unsigned short sB[128 * 32];

    const int tid  = threadIdx.x;
    const int wave = tid >> 6, lane = tid & 63;
    const int l = lane & 15, q16 = lane >> 4;
    const int wm = wave >> 1, wn = wave & 1;
    const int bid = blockIdx.x;                  // 0..767
    const int slot = bid >> 3;                   // 0..95
    const int m0 = ((bid & 7) * 8 + slot / 12) * 128;
    const int n0 = (slot % 12) * 128;

    f32x4 acc[4][4];
#pragma unroll
    for (int i = 0; i < 4; ++i)
#pragma unroll
        for (int j = 0; j < 4; ++j)
            acc[i][j] = (f32x4){0.f, 0.f, 0.f, 0.f};

    for (int k0 = 0; k0 < K; k0 += 32) {
#pragma unroll
        for (int call = 0; call < 2; ++call) {
            int L = call * 256 + tid;
            int r = L >> 2, c = L & 3;
            async16(A + (size_t)(m0 + r) * K + k0 + c * 8, sA + L * 8);
            async16(B + (size_t)(n0 + r) * K + k0 + c * 8, sB + L * 8);
        }
        __syncthreads();

        bf16x8 af[4], bfr[4];
#pragma unroll
        for (int i = 0; i < 4; ++i)
            af[i] = *(const bf16x8*)(sA + ((wm * 64 + i * 16 + l) * 4 + q16) * 8);
#pragma unroll
        for (int j = 0; j < 4; ++j)
            bfr[j] = *(const bf16x8*)(sB + ((wn * 64 + j * 16 + l) * 4 + q16) * 8);
#pragma unroll
        for (int i = 0; i < 4; ++i)
#pragma unroll
            for (int j = 0; j < 4; ++j)
                acc[i][j] = MFMA16(af[i], bfr[j], acc[i][j]);
        __syncthreads();
    }

    const float lscale = 0.18033688f;  // D^-0.5 * log2(e), folded into q
#pragma unroll
    for (int i = 0; i < 4; ++i) {
#pragma unroll
        for (int j = 0; j < 4; ++j) {
            int col = n0 + wn * 64 + j * 16 + l;
            float bv = bias[col];
#pragma unroll
            for (int r = 0; r < 4; ++r) {
                int row = m0 + wm * 64 + i * 16 + q16 * 4 + r;
                float val = acc[i][j][r] + bv;
                int which = col >> 9;            // 0:q 1:k 2:v
                int h = (col >> 6) & 7, d = col & 63;
                int b = row >> 11, n = row & 2047;
                if (which == 0)
                    out0[(size_t)(((b * 8 + h) * 2048) + n) * 64 + d] = f2bf(val * lscale);
                else if (which == 1)
                    out1[(size_t)(((b * 8 + h) * 2048) + n) * 64 + d] = f2bf(val);
                else {
                    // V^T with pi(n): swap bits 2<->3 of n (within 32-blocks)
                    int np = (n & ~12) | ((n & 8) >> 1) | ((n & 4) << 1);
                    out2[(size_t)(((b * 8 + h) * 64) + d) * 2048 + np] = f2bf(val);
                }
            }
        }
    }
}

// ---------------------------------------------------------------------------
// Output GEMM: 64x128 tile / 4 waves; BK=32; 4 blocks/CU. fp32 out + bias.
// XCD remap: XCD k owns rows [16k,16k+16) x 4 col-tiles.
// ---------------------------------------------------------------------------
__global__ __launch_bounds__(256, 4)
void gemm_out(const unsigned short* __restrict__ A,
              const unsigned short* __restrict__ B,
              const float* __restrict__ bias,
              float* __restrict__ outf,
              int K, int N)
{
    __shared__ unsigned short sA[64 * 32];
    __shared__ unsigned short sB[128 * 32];

    const int tid  = threadIdx.x;
    const int wave = tid >> 6, lane = tid & 63;
    const int l = lane & 15, q16 = lane >> 4;
    const int wm = wave >> 1, wn = wave & 1;
    const int bid = blockIdx.x;                  // 0..511
    const int slot = bid >> 3;                   // 0..63
    const int m0 = ((bid & 7) * 16 + (slot >> 2)) * 64;
    const int n0 = (slot & 3) * 128;

    f32x4 acc[2][4];
#pragma unroll
    for (int i = 0; i < 2; ++i)
#pragma unroll
        for (int j = 0; j < 4; ++j)
            acc[i][j] = (f32x4){0.f, 0.f, 0.f, 0.f};

    for (int k0 = 0; k0 < K; k0 += 32) {
        {
            int r = tid >> 2, c = tid & 3;       // A: 256 slots
            async16(A + (size_t)(m0 + r) * K + k0 + c * 8, sA + tid * 8);
        }
#pragma unroll
        for (int call = 0; call < 2; ++call) {   // B: 512 slots
            int L = call * 256 + tid;
            int r = L >> 2, c = L & 3;
            async16(B + (size_t)(n0 + r) * K + k0 + c * 8, sB + L * 8);
        }
        __syncthreads();

        bf16x8 af[2], bfr[4];
#pragma unroll
        for (int i = 0; i < 2; ++i)
            af[i] = *(const bf16x8*)(sA + ((wm * 32 + i * 16 + l) * 4 + q16) * 8);
#pragma unroll
        for (int j = 0; j < 4; ++j)
            bfr[j] = *(const bf16x8*)(sB + ((wn * 64 + j * 16 + l) * 4 + q16) * 8);
#pragma unroll
        for (int i = 0; i < 2; ++i)
#pragma unroll
            for (int j = 0; j < 4; ++j)
                acc[i][j] = MFMA16(af[i], bfr[j], acc[i][j]);
        __syncthreads();
    }

#pragma unroll
    for (int i = 0; i < 2; ++i) {
#pragma unroll
        for (int j = 0; j < 4; ++j) {
            int col = n0 + wn * 64 + j * 16 + l;
            float bv = bias[col];
#pragma unroll
            for (int r = 0; r < 4; ++r) {
                int row = m0 + wm * 32 + i * 16 + q16 * 4 + r;
                outf[(size_t)row * N + col] = acc[i][j][r] + bv;
            }
        }
    }
}

// ---------------------------------------------------------------------------
// Flash attention R21: 1024 threads / 16 waves / 1 block per CU.
// Wave (qq,kh): q-rows qq*32..+31 vs kv-half kh*64..+63 of each 128-kv tile.
// Triple-buffered LDS (96KB), depth-2 prefetch, counted vmcnt(2) waits
// BEFORE raw s_barrier (no vmcnt(0) drain in the main loop). setprio(1)
// around MFMA clusters. kh-partials merged additively via LDS epilogue.
// ---------------------------------------------------------------------------
__global__ __launch_bounds__(1024, 4)
void attn_fused(const unsigned short* __restrict__ Q,
                const unsigned short* __restrict__ Km,
                const unsigned short* __restrict__ Vt,
                unsigned short* __restrict__ O)
{
    __shared__ unsigned short sAll[49152];       // 96 KB: K[3][8192] | V[3][8192]

    const int tid  = threadIdx.x;
    const int wave = tid >> 6, lane = tid & 63;
    const int l31 = lane & 31, h = lane >> 5;
    const int swz = l31 & 7;
    const int qq = wave >> 1, kh = wave & 1;     // qq 0..7, kh 0..1
    const int bid = blockIdx.x;                  // 0..255
    const int slot = bid >> 3;                   // 0..31
    const int bh = (bid & 7) * 4 + (slot >> 3);  // 4 heads per XCD
    const int qc = slot & 7;                     // q-chunk of 256 rows
    const int q0 = qc * 256 + qq * 32;           // this wave: q0..q0+31

    const unsigned short* Kp = Km + (size_t)bh * 2048 * 64;
    const unsigned short* Vp = Vt + (size_t)bh * 64 * 2048;
    unsigned short* sKf = sAll;                  // 3 x 8192-elem K buffers
    unsigned short* sVf = sAll + 24576;          // 3 x 8192-elem V buffers

    // K fragment addrs: row = kh*64 + mt*32 + l31 (row&7 == swz),
    // chunk = (ks*2+h)^swz. mt*2048 added at use.
    int ka[4], va[2][2];
#pragma unroll
    for (int ks = 0; ks < 4; ++ks)
        ka[ks] = (kh * 64 + l31) * 64 + ((ks * 2 + h) ^ swz) * 8;
    // V^T fragment addrs: row = d = l31 (+dt*32 at use), kv chunk
    // (m1*4+ks2*2+h)^swz within kh's 64-col half.
#pragma unroll
    for (int m1 = 0; m1 < 2; ++m1)
#pragma unroll
        for (int ks2 = 0; ks2 < 2; ++ks2)
            va[m1][ks2] = l31 * 128 + ((m1 * 4 + ks2 * 2 + h) ^ swz) * 8 + kh * 64;

    // staging: 1024 slots of 8 elems, 1024 threads -> 1 K slot + 1 V slot each
    const int s = tid;
    const int rk = s >> 3;
    const int ksrc = rk * 64 + ((s & 7) ^ (rk & 7)) * 8;
    const int rv = s >> 4;
    const int vsrc = rv * 2048 + ((s & 15) ^ (rv & 7)) * 8;
    const int dsl = s * 8;

    bf16x8 qf[4];
#pragma unroll
    for (int ks = 0; ks < 4; ++ks)
        qf[ks] = *(const bf16x8*)(Q + (size_t)(bh * 2048 + q0 + l31) * 64
                                  + ks * 16 + h * 8);

    f32x16 oacc[2];
#pragma unroll
    for (int dt = 0; dt < 2; ++dt)
#pragma unroll
        for (int e = 0; e < 16; ++e) oacc[dt][e] = 0.f;
    f32x16 Zv;
#pragma unroll
    for (int e = 0; e < 16; ++e) Zv[e] = 0.f;
    f32x2 l2 = {0.f, 0.f};

    // prologue: stage tiles 0 and 1; wait own tile-0 loads; publish.
    async16(Kp + ksrc, (void*)(sKf + dsl));                    // K t0
    async16(Vp + vsrc, (void*)(sVf + dsl));                    // V t0
    async16(Kp + (size_t)128 * 64 + ksrc, (void*)(sKf + 8192 + dsl));  // K t1
    async16(Vp + (size_t)128 + vsrc, (void*)(sVf + 8192 + dsl));       // V t1
    asm volatile("s_waitcnt vmcnt(2)" ::: "memory");
    __builtin_amdgcn_s_barrier();
    __builtin_amdgcn_sched_barrier(0);

    int off0 = 0, off1 = 8192, off2 = 16384;     // cur, +1, +2 buffer offsets

    for (int it = 0; it < 16; ++it) {
        // issue tile it+2 into off2 (overwrites tile it-1's buffer)
        if (it < 14) {
            size_t kv = (size_t)(it + 2) * 128;
            async16(Kp + kv * 64 + ksrc, (void*)(sKf + off2 + dsl));
            async16(Vp + kv + vsrc, (void*)(sVf + off2 + dsl));
        }

        // QK^T for this wave's kv-half: 8 K reads feed 8 MFMAs.
        const unsigned short* sKc = sKf + off0;
        const unsigned short* sVc = sVf + off0;
        f32x16 sacc[2];
        {
            bf16x8 kf00 = *(const bf16x8*)(sKc + ka[0]);
            bf16x8 kf01 = *(const bf16x8*)(sKc + ka[0] + 2048);
            __builtin_amdgcn_s_setprio(1);
            sacc[0] = MFMA32(kf00, qf[0], Zv);
            sacc[1] = MFMA32(kf01, qf[0], Zv);
            __builtin_amdgcn_s_setprio(0);
#pragma unroll
            for (int ks = 1; ks < 4; ++ks) {
                bf16x8 kf0 = *(const bf16x8*)(sKc + ka[ks]);
                bf16x8 kf1 = *(const bf16x8*)(sKc + ka[ks] + 2048);
                __builtin_amdgcn_s_setprio(1);
                sacc[0] = MFMA32(kf0, qf[ks], sacc[0]);
                sacc[1] = MFMA32(kf1, qf[ks], sacc[1]);
                __builtin_amdgcn_s_setprio(0);
            }
        }

        // softmax + PV fused per 32-kv subtile mt; 8 V reads feed 8 MFMAs.
#pragma unroll
        for (int mt = 0; mt < 2; ++mt) {
            unsigned int pk[4][2];
#pragma unroll
            for (int g = 0; g < 4; ++g) {
                float p0 = fexp2(sacc[mt][4 * g + 0]);
                float p1 = fexp2(sacc[mt][4 * g + 1]);
                float p2 = fexp2(sacc[mt][4 * g + 2]);
                float p3 = fexp2(sacc[mt][4 * g + 3]);
                l2 += (f32x2){p0, p1};
                l2 += (f32x2){p2, p3};
                pk[g][0] = __builtin_amdgcn_perm(
                    __builtin_bit_cast(unsigned int, p1),
                    __builtin_bit_cast(unsigned int, p0), 0x07060302u);
                pk[g][1] = __builtin_amdgcn_perm(
                    __builtin_bit_cast(unsigned int, p3),
                    __builtin_bit_cast(unsigned int, p2), 0x07060302u);
            }
#pragma unroll
            for (int ks2 = 0; ks2 < 2; ++ks2) {
                u32x4 bu;
                bu[0] = pk[2 * ks2][0];
                bu[1] = pk[2 * ks2][1];
                bu[2] = pk[2 * ks2 + 1][0];
                bu[3] = pk[2 * ks2 + 1][1];
                bf16x8 bfrag = __builtin_bit_cast(bf16x8, bu);
#pragma unroll
                for (int dt = 0; dt < 2; ++dt) {
                    bf16x8 vf = *(const bf16x8*)(sVc + va[mt][ks2] + dt * 4096);
                    __builtin_amdgcn_s_setprio(1);
                    oacc[dt] = MFMA32(vf, bfrag, oacc[dt]);
                    __builtin_amdgcn_s_setprio(0);
                }
            }
        }

        // counted wait BEFORE barrier: tile it+1 complete (its 2 loads are
        // the oldest outstanding); tile it+2's 2 loads stay in flight.
        if (it < 14) {
            asm volatile("s_waitcnt vmcnt(2)" ::: "memory");
        } else if (it == 14) {
            asm volatile("s_waitcnt vmcnt(0)" ::: "memory");
        }
        if (it < 15) {
            asm volatile("s_waitcnt lgkmcnt(0)" ::: "memory");
            __builtin_amdgcn_s_barrier();
            __builtin_amdgcn_sched_barrier(0);
        }

        int t = off0; off0 = off1; off1 = off2; off2 = t;
    }

    // ---- kh-half merge epilogue ----
    // kh=1 waves park partials in LDS; kh=0 waves add and write O.
    __syncthreads();
    float* sf = (float*)sAll;            // 64 KB: oacc partials (8 waves x 8KB)
    float* sl = sf + 16384;              // 4 KB: l2 partials
    if (kh == 1) {
        const int base = qq * 2048 + lane * 32;
#pragma unroll
        for (int dt = 0; dt < 2; ++dt) {
            int chunk = dt ^ (lane & 1);         // bank de-phase
            *(f32x16*)(sf + base + chunk * 16) = oacc[dt];
        }
        *(f32x2*)(sl + qq * 128 + lane * 2) = l2;
    }
    __syncthreads();
    if (kh == 0) {
        const int base = qq * 2048 + lane * 32;
#pragma unroll
        for (int dt = 0; dt < 2; ++dt) {
            int chunk = dt ^ (lane & 1);
            f32x16 part = *(const f32x16*)(sf + base + chunk * 16);
#pragma unroll
            for (int e = 0; e < 16; ++e) oacc[dt][e] += part[e];
        }
        l2 += *(const f32x2*)(sl + qq * 128 + lane * 2);

        float l_run = l2[0] + l2[1];
        l_run += __shfl_xor(l_run, 32);
        float inv = 1.f / fmaxf(l_run, 1e-20f);
        const int b = bh >> 3, hh = bh & 7;
        unsigned short* obase = O + ((size_t)(b * 2048 + q0 + l31)) * 512 + hh * 64;
#pragma unroll
        for (int dt = 0; dt < 2; ++dt)
#pragma unroll
            for (int g = 0; g < 4; ++g) {
                int d = dt * 32 + 8 * g + 4 * h;
                unsigned int w0 = pk2(oacc[dt][4 * g + 0] * inv,
                                      oacc[dt][4 * g + 1] * inv);
                unsigned int w1 = pk2(oacc[dt][4 * g + 2] * inv,
                                      oacc[dt][4 * g + 3] * inv);
                uint2 w = {w0, w1};
                *(uint2*)(obase + d) = w;
            }
    }
}

// ---------------------------------------------------------------------------
extern "C" void kernel_launch(void* const* d_in, const int* in_sizes, int n_in,
                              void* d_out, int out_size, void* d_ws, size_t ws_size,
                              hipStream_t stream)
{
    const float* x      = (const float*)d_in[0];  // [4,2048,512]
    const float* qkv_w  = (const float*)d_in[1];  // [1536,512]
    const float* qkv_b  = (const float*)d_in[2];  // [1536]
    const float* proj_w = (const float*)d_in[3];  // [512,512]
    const float* proj_b = (const float*)d_in[4];  // [512]

    const size_t PER = 4u * 8u * 2048u * 64u;     // 4,194,304 elems (8 MB bf16)
    unsigned short* q_ws  = (unsigned short*)d_ws;
    unsigned short* k_ws  = q_ws  + PER;
    unsigned short* vt_ws = k_ws  + PER;
    unsigned short* ao_ws = vt_ws + PER;
    unsigned short* wb2   = ao_ws + PER;          // proj_w bf16 (0.5 MB)

    // bf16 scratch inside d_out (16 MB; dead until final GEMM overwrites it)
    unsigned short* xb = (unsigned short*)d_out;          // 8 MB
    unsigned short* wb = xb + PER;                        // 1.5 MB

    // 0) bulk fp32->bf16 of x, qkv_w, proj_w (one launch)
    cvt_bf16<<<dim3(640), 256, 0, stream>>>(x, qkv_w, proj_w, xb, wb, wb2);
    // 1) QKV projection: M=8192, N=1536, K=512 (XCD-remapped)
    gemm_qkv<<<dim3(768), 256, 0, stream>>>(xb, wb, qkv_b, q_ws, k_ws, vt_ws, 512);
    // 2) Flash attention: 256 blocks x 1024 threads, depth-2 pipeline
    attn_fused<<<dim3(256), 1024, 0, stream>>>(q_ws, k_ws, vt_ws, ao_ws);
    // 3) Output projection: M=8192, N=512, K=512 (XCD-remapped)
    gemm_out<<<dim3(512), 256, 0, stream>>>(ao_ws, wb2, proj_b, (float*)d_out, 512, 512);
}

// Round 5
// 154.101 us; speedup vs baseline: 1.0289x; 1.0113x over previous
//
#include <hip/hip_runtime.h>
#include <stdint.h>

// ---------------------------------------------------------------------------
// Fused MHA block: qkv proj -> flash attention -> out proj.
// Inputs fp32, output fp32; bf16 MFMA compute, fp32 accum.
// B=4 N=2048 C=512 H=8 D=64 fixed.
// R22: attn_fused = R19 work decomposition x R21 pipeline.
// 512 threads / 8 waves, wave (qq,kh) owns 64 q-rows x 64 kv-cols: 16
// ds_read_b128 feed 32 MFMA32 per wave-iter (1:2 — halves the LDS pipe
// cost that bounds R21's 1:1 layout at ~4300 cyc/iter/CU). Triple-buffered
// 96KB LDS, depth-2 prefetch, counted vmcnt(4) before raw s_barrier (no
// vmcnt(0) drain in main loop). 1 block/CU. kh merge via LDS epilogue.
// ---------------------------------------------------------------------------

typedef short bf16x8 __attribute__((ext_vector_type(8)));   // 8 bf16 = 4 VGPRs
typedef float f32x2  __attribute__((ext_vector_type(2)));
typedef float f32x4  __attribute__((ext_vector_type(4)));
typedef float f32x16 __attribute__((ext_vector_type(16)));
typedef unsigned int u32x4 __attribute__((ext_vector_type(4)));

__device__ __forceinline__ unsigned short f2bf(float f) {
    unsigned int u = __builtin_bit_cast(unsigned int, f);
    u += 0x7fffu + ((u >> 16) & 1u);
    return (unsigned short)(u >> 16);
}
__device__ __forceinline__ unsigned int pk2(float a, float b) {
    return (unsigned int)f2bf(a) | ((unsigned int)f2bf(b) << 16);
}
__device__ __forceinline__ float fexp2(float x) {
    return __builtin_amdgcn_exp2f(x);    // bare v_exp_f32
}
__device__ __forceinline__ bf16x8 ld8_f32(const float* __restrict__ p) {
    float4 f0 = *(const float4*)p;
    float4 f1 = *(const float4*)(p + 4);
    u32x4 u = {pk2(f0.x, f0.y), pk2(f0.z, f0.w), pk2(f1.x, f1.y), pk2(f1.z, f1.w)};
    return __builtin_bit_cast(bf16x8, u);
}
__device__ __forceinline__ void async16(const void* g, void* l) {
    __builtin_amdgcn_global_load_lds(
        (const __attribute__((address_space(1))) unsigned int*)g,
        (__attribute__((address_space(3))) unsigned int*)l,
        16, 0, 0);
}

#define MFMA16(a, b, c) __builtin_amdgcn_mfma_f32_16x16x32_bf16((a), (b), (c), 0, 0, 0)
#define MFMA32(a, b, c) __builtin_amdgcn_mfma_f32_32x32x16_bf16((a), (b), (c), 0, 0, 0)

// ---------------------------------------------------------------------------
// fp32 -> bf16 bulk convert: x, qkv_w, proj_w in one pass.
// ---------------------------------------------------------------------------
__global__ void cvt_bf16(const float* __restrict__ x,
                         const float* __restrict__ w,
                         const float* __restrict__ w2,
                         unsigned short* __restrict__ xb,
                         unsigned short* __restrict__ wb,
                         unsigned short* __restrict__ wb2)
{
    const int G = 524288 + 98304 + 32768;
    for (int idx = blockIdx.x * 256 + threadIdx.x; idx < G; idx += gridDim.x * 256) {
        if (idx < 524288)
            *(bf16x8*)(xb + (size_t)idx * 8) = ld8_f32(x + (size_t)idx * 8);
        else if (idx < 524288 + 98304) {
            int j = idx - 524288;
            *(bf16x8*)(wb + (size_t)j * 8) = ld8_f32(w + (size_t)j * 8);
        } else {
            int j = idx - 524288 - 98304;
            *(bf16x8*)(wb2 + (size_t)j * 8) = ld8_f32(w2 + (size_t)j * 8);
        }
    }
}

// ---------------------------------------------------------------------------
// QKV GEMM: 128x128 tile / 4 waves; BK=32; dual DMA staging; 4 blocks/CU.
// XCD remap: XCD k owns A-rows [8k,8k+8) x all 12 col-tiles.
// ---------------------------------------------------------------------------
__global__ __launch_bounds__(256, 4)
void gemm_qkv(const unsigned short* __restrict__ A,
              const unsigned short* __restrict__ B,
              const float* __restrict__ bias,
              unsigned short* __restrict__ out0,
              unsigned short* __restrict__ out1,
              unsigned short* __restrict__ out2,
              int K)
{
    __shared__ unsigned short sA[128 * 32];
    __shared__ unsigned short sB[128 * 32];

    const int tid  = threadIdx.x;
    const int wave = tid >> 6, lane = tid & 63;
    const int l = lane & 15, q16 = lane >> 4;
    const int wm = wave >> 1, wn = wave & 1;
    const int bid = blockIdx.x;                  // 0..767
    const int slot = bid >> 3;                   // 0..95
    const int m0 = ((bid & 7) * 8 + slot / 12) * 128;
    const int n0 = (slot % 12) * 128;

    f32x4 acc[4][4];
#pragma unroll
    for (int i = 0; i < 4; ++i)
#pragma unroll
        for (int j = 0; j < 4; ++j)
            acc[i][j] = (f32x4){0.f, 0.f, 0.f, 0.f};

    for (int k0 = 0; k0 < K; k0 += 32) {
#pragma unroll
        for (int call = 0; call < 2; ++call) {
            int L = call * 256 + tid;
            int r = L >> 2, c = L & 3;
            async16(A + (size_t)(m0 + r) * K + k0 + c * 8, sA + L * 8);
            async16(B + (size_t)(n0 + r) * K + k0 + c * 8, sB + L * 8);
        }
        __syncthreads();

        bf16x8 af[4], bfr[4];
#pragma unroll
        for (int i = 0; i < 4; ++i)
            af[i] = *(const bf16x8*)(sA + ((wm * 64 + i * 16 + l) * 4 + q16) * 8);
#pragma unroll
        for (int j = 0; j < 4; ++j)
            bfr[j] = *(const bf16x8*)(sB + ((wn * 64 + j * 16 + l) * 4 + q16) * 8);
#pragma unroll
        for (int i = 0; i < 4; ++i)
#pragma unroll
            for (int j = 0; j < 4; ++j)
                acc[i][j] = MFMA16(af[i], bfr[j], acc[i][j]);
        __syncthreads();
    }

    const float lscale = 0.18033688f;  // D^-0.5 * log2(e), folded into q
#pragma unroll
    for (int i = 0; i < 4; ++i) {
#pragma unroll
        for (int j = 0; j < 4; ++j) {
            int col = n0 + wn * 64 + j * 16 + l;
            float bv = bias[col];
#pragma unroll
            for (int r = 0; r < 4; ++r) {
                int row = m0 + wm * 64 + i * 16 + q16 * 4 + r;
                float val = acc[i][j][r] + bv;
                int which = col >> 9;            // 0:q 1:k 2:v
                int h = (col >> 6) & 7, d = col & 63;
                int b = row >> 11, n = row & 2047;
                if (which == 0)
                    out0[(size_t)(((b * 8 + h) * 2048) + n) * 64 + d] = f2bf(val * lscale);
                else if (which == 1)
                    out1[(size_t)(((b * 8 + h) * 2048) + n) * 64 + d] = f2bf(val);
                else {
                    // V^T with pi(n): swap bits 2<->3 of n (within 32-blocks)
                    int np = (n & ~12) | ((n & 8) >> 1) | ((n & 4) << 1);
                    out2[(size_t)(((b * 8 + h) * 64) + d) * 2048 + np] = f2bf(val);
                }
            }
        }
    }
}

// ---------------------------------------------------------------------------
// Output GEMM: 64x128 tile / 4 waves; BK=32; 4 blocks/CU. fp32 out + bias.
// XCD remap: XCD k owns rows [16k,16k+16) x 4 col-tiles.
// ---------------------------------------------------------------------------
__global__ __launch_bounds__(256, 4)
void gemm_out(const unsigned short* __restrict__ A,
              const unsigned short* __restrict__ B,
              const float* __restrict__ bias,
              float* __restrict__ outf,
              int K, int N)
{
    __shared__ unsigned short sA[64 * 32];
    __shared__ unsigned short sB[128 * 32];

    const int tid  = threadIdx.x;
    const int wave = tid >> 6, lane = tid & 63;
    const int l = lane & 15, q16 = lane >> 4;
    const int wm = wave >> 1, wn = wave & 1;
    const int bid = blockIdx.x;                  // 0..511
    const int slot = bid >> 3;                   // 0..63
    const int m0 = ((bid & 7) * 16 + (slot >> 2)) * 64;
    const int n0 = (slot & 3) * 128;

    f32x4 acc[2][4];
#pragma unroll
    for (int i = 0; i < 2; ++i)
#pragma unroll
        for (int j = 0; j < 4; ++j)
            acc[i][j] = (f32x4){0.f, 0.f, 0.f, 0.f};

    for (int k0 = 0; k0 < K; k0 += 32) {
        {
            int r = tid >> 2, c = tid & 3;       // A: 256 slots
            async16(A + (size_t)(m0 + r) * K + k0 + c * 8, sA + tid * 8);
        }
#pragma unroll
        for (int call = 0; call < 2; ++call) {   // B: 512 slots
            int L = call * 256 + tid;
            int r = L >> 2, c = L & 3;
            async16(B + (size_t)(n0 + r) * K + k0 + c * 8, sB + L * 8);
        }
        __syncthreads();

        bf16x8 af[2], bfr[4];
#pragma unroll
        for (int i = 0; i < 2; ++i)
            af[i] = *(const bf16x8*)(sA + ((wm * 32 + i * 16 + l) * 4 + q16) * 8);
#pragma unroll
        for (int j = 0; j < 4; ++j)
            bfr[j] = *(const bf16x8*)(sB + ((wn * 64 + j * 16 + l) * 4 + q16) * 8);
#pragma unroll
        for (int i = 0; i < 2; ++i)
#pragma unroll
            for (int j = 0; j < 4; ++j)
                acc[i][j] = MFMA16(af[i], bfr[j], acc[i][j]);
        __syncthreads();
    }

#pragma unroll
    for (int i = 0; i < 2; ++i) {
#pragma unroll
        for (int j = 0; j < 4; ++j) {
            int col = n0 + wn * 64 + j * 16 + l;
            float bv = bias[col];
#pragma unroll
            for (int r = 0; r < 4; ++r) {
                int row = m0 + wm * 32 + i * 16 + q16 * 4 + r;
                outf[(size_t)row * N + col] = acc[i][j][r] + bv;
            }
        }
    }
}

// ---------------------------------------------------------------------------
// Flash attention R22: 512 threads / 8 waves / 1 block per CU.
// Wave (qq,kh): q-rows qq*64..+63 (qt 0,1) vs kv-half kh*64..+63.
// Each K/V fragment read feeds 2 MFMAs (qt) -> 16 reads : 32 MFMAs per
// wave-iter. Triple-buffered LDS (96KB), depth-2 prefetch, counted
// vmcnt(4) before raw s_barrier. setprio(1) around MFMA clusters.
// kh-partials merged additively via LDS epilogue (static-max softmax).
// ---------------------------------------------------------------------------
__global__ __launch_bounds__(512, 2)
void attn_fused(const unsigned short* __restrict__ Q,
                const unsigned short* __restrict__ Km,
                const unsigned short* __restrict__ Vt,
                unsigned short* __restrict__ O)
{
    __shared__ unsigned short sAll[49152];       // 96 KB: K[3][8192] | V[3][8192]

    const int tid  = threadIdx.x;
    const int wave = tid >> 6, lane = tid & 63;
    const int l31 = lane & 31, h = lane >> 5;
    const int swz = l31 & 7;
    const int qq = wave >> 1, kh = wave & 1;     // qq 0..3, kh 0..1
    const int bid = blockIdx.x;                  // 0..255
    const int slot = bid >> 3;                   // 0..31
    const int bh = (bid & 7) * 4 + (slot >> 3);  // 4 heads per XCD
    const int qc = slot & 7;                     // q-chunk of 256 rows
    const int q0 = qc * 256 + qq * 64;           // this wave: q0..q0+63

    const unsigned short* Kp = Km + (size_t)bh * 2048 * 64;
    const unsigned short* Vp = Vt + (size_t)bh * 64 * 2048;
    unsigned short* sKf = sAll;                  // 3 x 8192-elem K buffers
    unsigned short* sVf = sAll + 24576;          // 3 x 8192-elem V buffers

    // K fragment addrs: row = kh*64 + mt*32 + l31 (row&7 == swz),
    // chunk = (ks*2+h)^swz. mt*2048 added at use.
    int ka[4], va[2][2];
#pragma unroll
    for (int ks = 0; ks < 4; ++ks)
        ka[ks] = (kh * 64 + l31) * 64 + ((ks * 2 + h) ^ swz) * 8;
    // V^T fragment addrs: row = d = l31 (+dt*32 via +4096), kv chunk
    // (mt*4+ks2*2+h)^swz within kh's 64-col half (+kh*64 raw offset).
#pragma unroll
    for (int m1 = 0; m1 < 2; ++m1)
#pragma unroll
        for (int ks2 = 0; ks2 < 2; ++ks2)
            va[m1][ks2] = l31 * 128 + ((m1 * 4 + ks2 * 2 + h) ^ swz) * 8 + kh * 64;

    // staging: 1024 slots of 8 elems, 512 threads -> 2 K slots + 2 V slots
    int ksrc[2], vsrc[2], dsl[2];
#pragma unroll
    for (int c = 0; c < 2; ++c) {
        int s = c * 512 + tid;
        int rk = s >> 3;
        ksrc[c] = rk * 64 + ((s & 7) ^ (rk & 7)) * 8;
        int rv = s >> 4;
        vsrc[c] = rv * 2048 + ((s & 15) ^ (rv & 7)) * 8;
        dsl[c] = s * 8;
    }

    bf16x8 qf[2][4];
#pragma unroll
    for (int qt = 0; qt < 2; ++qt)
#pragma unroll
        for (int ks = 0; ks < 4; ++ks)
            qf[qt][ks] = *(const bf16x8*)(Q + (size_t)(bh * 2048 + q0 + qt * 32 + l31) * 64
                                          + ks * 16 + h * 8);

    f32x16 oacc[2][2];
#pragma unroll
    for (int qt = 0; qt < 2; ++qt)
#pragma unroll
        for (int dt = 0; dt < 2; ++dt)
#pragma unroll
            for (int e = 0; e < 16; ++e) oacc[qt][dt][e] = 0.f;
    f32x16 Zv;
#pragma unroll
    for (int e = 0; e < 16; ++e) Zv[e] = 0.f;
    f32x2 l2[2];
    l2[0] = (f32x2){0.f, 0.f};
    l2[1] = (f32x2){0.f, 0.f};

    // prologue: stage tiles 0 and 1 (4 loads each per thread: K,K,V,V);
    // wait tile-0's 4 loads (4 newest = tile 1 still in flight); publish.
#pragma unroll
    for (int c = 0; c < 2; ++c) {
        async16(Kp + ksrc[c], (void*)(sKf + dsl[c]));
        async16(Vp + vsrc[c], (void*)(sVf + dsl[c]));
    }
#pragma unroll
    for (int c = 0; c < 2; ++c) {
        async16(Kp + (size_t)128 * 64 + ksrc[c], (void*)(sKf + 8192 + dsl[c]));
        async16(Vp + (size_t)128 + vsrc[c], (void*)(sVf + 8192 + dsl[c]));
    }
    asm volatile("s_waitcnt vmcnt(4)" ::: "memory");
    __builtin_amdgcn_s_barrier();
    __builtin_amdgcn_sched_barrier(0);

    int off0 = 0, off1 = 8192, off2 = 16384;     // cur, +1, +2 buffer offsets

    for (int it = 0; it < 16; ++it) {
        // issue tile it+2 into off2 (overwrites tile it-1's buffer)
        if (it < 14) {
            size_t kv = (size_t)(it + 2) * 128;
#pragma unroll
            for (int c = 0; c < 2; ++c) {
                async16(Kp + kv * 64 + ksrc[c], (void*)(sKf + off2 + dsl[c]));
                async16(Vp + kv + vsrc[c], (void*)(sVf + off2 + dsl[c]));
            }
        }

        // QK^T for this wave's kv-half: 8 K reads feed 16 MFMAs (qt 0,1).
        const unsigned short* sKc = sKf + off0;
        const unsigned short* sVc = sVf + off0;
        f32x16 sacc[2][2];
#pragma unroll
        for (int mt = 0; mt < 2; ++mt) {
            bf16x8 kf0 = *(const bf16x8*)(sKc + ka[0] + mt * 2048);
            __builtin_amdgcn_s_setprio(1);
            sacc[0][mt] = MFMA32(kf0, qf[0][0], Zv);
            sacc[1][mt] = MFMA32(kf0, qf[1][0], Zv);
            __builtin_amdgcn_s_setprio(0);
#pragma unroll
            for (int ks = 1; ks < 4; ++ks) {
                bf16x8 kf = *(const bf16x8*)(sKc + ka[ks] + mt * 2048);
                __builtin_amdgcn_s_setprio(1);
                sacc[0][mt] = MFMA32(kf, qf[0][ks], sacc[0][mt]);
                sacc[1][mt] = MFMA32(kf, qf[1][ks], sacc[1][mt]);
                __builtin_amdgcn_s_setprio(0);
            }
        }

        // softmax + PV fused per 32-kv subtile mt; 8 V reads feed 16 MFMAs.
#pragma unroll
        for (int mt = 0; mt < 2; ++mt) {
            unsigned int pk[2][4][2];
#pragma unroll
            for (int qt = 0; qt < 2; ++qt) {
#pragma unroll
                for (int g = 0; g < 4; ++g) {
                    float p0 = fexp2(sacc[qt][mt][4 * g + 0]);
                    float p1 = fexp2(sacc[qt][mt][4 * g + 1]);
                    float p2 = fexp2(sacc[qt][mt][4 * g + 2]);
                    float p3 = fexp2(sacc[qt][mt][4 * g + 3]);
                    l2[qt] += (f32x2){p0, p1};
                    l2[qt] += (f32x2){p2, p3};
                    pk[qt][g][0] = __builtin_amdgcn_perm(
                        __builtin_bit_cast(unsigned int, p1),
                        __builtin_bit_cast(unsigned int, p0), 0x07060302u);
                    pk[qt][g][1] = __builtin_amdgcn_perm(
                        __builtin_bit_cast(unsigned int, p3),
                        __builtin_bit_cast(unsigned int, p2), 0x07060302u);
                }
            }
#pragma unroll
            for (int ks2 = 0; ks2 < 2; ++ks2) {
                u32x4 bu0, bu1;
                bu0[0] = pk[0][2 * ks2][0];
                bu0[1] = pk[0][2 * ks2][1];
                bu0[2] = pk[0][2 * ks2 + 1][0];
                bu0[3] = pk[0][2 * ks2 + 1][1];
                bu1[0] = pk[1][2 * ks2][0];
                bu1[1] = pk[1][2 * ks2][1];
                bu1[2] = pk[1][2 * ks2 + 1][0];
                bu1[3] = pk[1][2 * ks2 + 1][1];
                bf16x8 bf0 = __builtin_bit_cast(bf16x8, bu0);
                bf16x8 bf1 = __builtin_bit_cast(bf16x8, bu1);
#pragma unroll
                for (int dt = 0; dt < 2; ++dt) {
                    bf16x8 vf = *(const bf16x8*)(sVc + va[mt][ks2] + dt * 4096);
                    __builtin_amdgcn_s_setprio(1);
                    oacc[0][dt] = MFMA32(vf, bf0, oacc[0][dt]);
                    oacc[1][dt] = MFMA32(vf, bf1, oacc[1][dt]);
                    __builtin_amdgcn_s_setprio(0);
                }
            }
        }

        // counted wait BEFORE barrier: tile it+1's 4 loads are the oldest
        // outstanding; tile it+2's 4 stay in flight.
        if (it < 14) {
            asm volatile("s_waitcnt vmcnt(4)" ::: "memory");
        } else if (it == 14) {
            asm volatile("s_waitcnt vmcnt(0)" ::: "memory");
        }
        if (it < 15) {
            asm volatile("s_waitcnt lgkmcnt(0)" ::: "memory");
            __builtin_amdgcn_s_barrier();
            __builtin_amdgcn_sched_barrier(0);
        }

        int t = off0; off0 = off1; off1 = off2; off2 = t;
    }

    // ---- kh-half merge epilogue ----
    // kh=1 waves park partials in LDS; kh=0 waves add and write O.
    __syncthreads();
    float* sf = (float*)sAll;            // 64 KB: oacc partials (4 qq x 64 ln x 64)
    float* sl = sf + 16384;              // 4 KB: l2 partials
    if (kh == 1) {
        const int base = (qq * 64 + lane) * 64;
#pragma unroll
        for (int qt = 0; qt < 2; ++qt)
#pragma unroll
            for (int dt = 0; dt < 2; ++dt) {
                int chunk = (qt * 2 + dt) ^ (lane & 3);   // bank de-phase
                *(f32x16*)(sf + base + chunk * 16) = oacc[qt][dt];
            }
        *(f32x2*)(sl + (qq * 64 + lane) * 4 + 0) = l2[0];
        *(f32x2*)(sl + (qq * 64 + lane) * 4 + 2) = l2[1];
    }
    __syncthreads();
    if (kh == 0) {
        const int base = (qq * 64 + lane) * 64;
#pragma unroll
        for (int qt = 0; qt < 2; ++qt)
#pragma unroll
            for (int dt = 0; dt < 2; ++dt) {
                int chunk = (qt * 2 + dt) ^ (lane & 3);
                f32x16 part = *(const f32x16*)(sf + base + chunk * 16);
#pragma unroll
                for (int e = 0; e < 16; ++e) oacc[qt][dt][e] += part[e];
            }
        l2[0] += *(const f32x2*)(sl + (qq * 64 + lane) * 4 + 0);
        l2[1] += *(const f32x2*)(sl + (qq * 64 + lane) * 4 + 2);

        const int b = bh >> 3, hh = bh & 7;
#pragma unroll
        for (int qt = 0; qt < 2; ++qt) {
            float l_run = l2[qt][0] + l2[qt][1];
            l_run += __shfl_xor(l_run, 32);
            float inv = 1.f / fmaxf(l_run, 1e-20f);
            unsigned short* obase = O + ((size_t)(b * 2048 + q0 + qt * 32 + l31)) * 512 + hh * 64;
#pragma unroll
            for (int dt = 0; dt < 2; ++dt)
#pragma unroll
                for (int g = 0; g < 4; ++g) {
                    int d = dt * 32 + 8 * g + 4 * h;
                    unsigned int w0 = pk2(oacc[qt][dt][4 * g + 0] * inv,
                                          oacc[qt][dt][4 * g + 1] * inv);
                    unsigned int w1 = pk2(oacc[qt][dt][4 * g + 2] * inv,
                                          oacc[qt][dt][4 * g + 3] * inv);
                    uint2 w = {w0, w1};
                    *(uint2*)(obase + d) = w;
                }
        }
    }
}

// ---------------------------------------------------------------------------
extern "C" void kernel_launch(void* const* d_in, const int* in_sizes, int n_in,
                              void* d_out, int out_size, void* d_ws, size_t ws_size,
                              hipStream_t stream)
{
    const float* x      = (const float*)d_in[0];  // [4,2048,512]
    const float* qkv_w  = (const float*)d_in[1];  // [1536,512]
    const float* qkv_b  = (const float*)d_in[2];  // [1536]
    const float* proj_w = (const float*)d_in[3];  // [512,512]
    const float* proj_b = (const float*)d_in[4];  // [512]

    const size_t PER = 4u * 8u * 2048u * 64u;     // 4,194,304 elems (8 MB bf16)
    unsigned short* q_ws  = (unsigned short*)d_ws;
    unsigned short* k_ws  = q_ws  + PER;
    unsigned short* vt_ws = k_ws  + PER;
    unsigned short* ao_ws = vt_ws + PER;
    unsigned short* wb2   = ao_ws + PER;          // proj_w bf16 (0.5 MB)

    // bf16 scratch inside d_out (16 MB; dead until final GEMM overwrites it)
    unsigned short* xb = (unsigned short*)d_out;          // 8 MB
    unsigned short* wb = xb + PER;                        // 1.5 MB

    // 0) bulk fp32->bf16 of x, qkv_w, proj_w (one launch)
    cvt_bf16<<<dim3(640), 256, 0, stream>>>(x, qkv_w, proj_w, xb, wb, wb2);
    // 1) QKV projection: M=8192, N=1536, K=512 (XCD-remapped)
    gemm_qkv<<<dim3(768), 256, 0, stream>>>(xb, wb, qkv_b, q_ws, k_ws, vt_ws, 512);
    // 2) Flash attention: 256 blocks x 512 threads, depth-2 pipeline
    attn_fused<<<dim3(256), 512, 0, stream>>>(q_ws, k_ws, vt_ws, ao_ws);
    // 3) Output projection: M=8192, N=512, K=512 (XCD-remapped)
    gemm_out<<<dim3(512), 256, 0, stream>>>(ao_ws, wb2, proj_b, (float*)d_out, 512, 512);
}